// Round 1
// baseline (407.755 us; speedup 1.0000x reference)
//
#include <hip/hip_runtime.h>
#include <hip/hip_bf16.h>
#include <stdint.h>

#define NSH 256
#define AG 512          // alpha grid
#define BG 252          // beta grid
#define AB (AG*BG)      // 129024
#define KK 1024
#define SENT 0xFFFFFFFFFFFFFFFFull

// monotone float->uint map: ascending uint == ascending float
static __device__ __forceinline__ unsigned int fkey(float v){
    unsigned int u = __float_as_uint(v);
    u ^= (u >> 31) ? 0xFFFFFFFFu : 0x80000000u;
    return u;
}

// ---------------- GEMV: f[j] = sum_i sig[i]*sh[i*AB+j], sequential FMA i=0..255
__global__ __launch_bounds__(256) void k_gemv(const float* __restrict__ sig,
        const float* __restrict__ sh1, const float* __restrict__ sh2,
        float* __restrict__ f){
    __shared__ float s[NSH];
    s[threadIdx.x] = sig[threadIdx.x];
    __syncthreads();
    const float* sh = blockIdx.y ? sh2 : sh1;
    float* fo = f + (size_t)blockIdx.y * AB;
    size_t j4 = ((size_t)blockIdx.x * 256 + threadIdx.x) * 4;
    const float* p = sh + j4;
    float a0 = 0.f, a1 = 0.f, a2 = 0.f, a3 = 0.f;
    #pragma unroll 8
    for (int i = 0; i < NSH; ++i){
        float4 v = *reinterpret_cast<const float4*>(p + (size_t)i * AB);
        float si = s[i];
        a0 = fmaf(si, v.x, a0);
        a1 = fmaf(si, v.y, a1);
        a2 = fmaf(si, v.z, a2);
        a3 = fmaf(si, v.w, a3);
    }
    float4 o; o.x = a0; o.y = a1; o.z = a2; o.w = a3;
    *reinterpret_cast<float4*>(fo + j4) = o;
}

// ---------------- mask + pack candidate keys (wave-aggregated atomics)
__global__ __launch_bounds__(256) void k_mask(const float* __restrict__ f,
        unsigned long long* __restrict__ cand, unsigned int* __restrict__ counts){
    int proj = blockIdx.y;
    const float* fp = f + (size_t)proj * AB;
    int j = blockIdx.x * 256 + threadIdx.x;
    bool pred = false;
    unsigned long long key = 0;
    {
        int a = j / BG, b = j - a * BG;
        if (a > 0 && a < AG - 1 && b > 0 && b < BG - 1){
            float v = fp[j];
            pred = (v > fp[j-1]) && (v > fp[j+1]) && (v > fp[j-BG]) && (v > fp[j+BG]);
            if (pred)
                key = (((unsigned long long)(~fkey(v))) << 32) | (unsigned int)j;
        }
    }
    unsigned long long bal = __ballot(pred);
    if (bal){
        int lane = threadIdx.x & 63;
        int leader = __ffsll(bal) - 1;
        unsigned int base = 0;
        if (lane == leader) base = atomicAdd(&counts[proj], (unsigned int)__popcll(bal));
        base = __shfl(base, leader);
        if (pred){
            unsigned int off = (unsigned int)__popcll(bal & ((1ull << lane) - 1ull));
            cand[(size_t)proj * AB + base + off] = key;
        }
    }
}

// ---------------- single-block radix-select of K smallest 64-bit keys
__global__ __launch_bounds__(1024) void k_select(const unsigned long long* __restrict__ cand,
        const unsigned int* __restrict__ counts, unsigned long long* __restrict__ sel){
    int proj = blockIdx.y;
    const unsigned long long* cp = cand + (size_t)proj * AB;
    unsigned long long* sp = sel + proj * KK;
    unsigned int count = counts[proj];
    int tid = threadIdx.x;
    if (count <= KK){
        if (tid < KK) sp[tid] = SENT;               // pad
        if (tid < (int)count) sp[tid] = cp[tid];    // same thread overwrites same slot
        return;
    }
    __shared__ unsigned int hist[256];
    __shared__ unsigned int sbin, sremk;
    unsigned long long prefix = 0, pmask = 0;
    unsigned int remk = KK;
    for (int lvl = 7; lvl >= 0; --lvl){
        int shft = lvl * 8;
        if (tid < 256) hist[tid] = 0;
        __syncthreads();
        for (unsigned int i = tid; i < count; i += 1024){
            unsigned long long k = cp[i];
            if ((k & pmask) == prefix)
                atomicAdd(&hist[(unsigned int)(k >> shft) & 255u], 1u);
        }
        __syncthreads();
        if (tid == 0){
            unsigned int c = 0;
            for (int b = 0; b < 256; ++b){
                unsigned int h = hist[b];
                if (c + h >= remk){ sbin = (unsigned int)b; sremk = remk - c; break; }
                c += h;
            }
        }
        __syncthreads();
        prefix |= ((unsigned long long)sbin) << shft;
        pmask  |= 0xFFull << shft;
        remk = sremk;
        __syncthreads();
    }
    // prefix == K-th smallest key (keys unique: value bits + index)
    __shared__ unsigned int pos;
    if (tid == 0) pos = 0;
    __syncthreads();
    for (unsigned int i = tid; i < count; i += 1024){
        unsigned long long k = cp[i];
        if (k <= prefix){
            unsigned int p = atomicAdd(&pos, 1u);
            sp[p] = k;
        }
    }
}

// ---------------- bitonic sort 1024 keys + gather peaks/radius/valid
__global__ __launch_bounds__(1024) void k_sortgather(const unsigned long long* __restrict__ sel,
        const float* __restrict__ f, const float* __restrict__ xyz1,
        const float* __restrict__ xyz2, float4* __restrict__ pr,
        unsigned int* __restrict__ vb, float* __restrict__ out){
    int proj = blockIdx.y;
    int tid = threadIdx.x;
    __shared__ unsigned long long s[KK];
    s[tid] = sel[proj * KK + tid];
    __syncthreads();
    for (int k = 2; k <= KK; k <<= 1){
        for (int j = k >> 1; j > 0; j >>= 1){
            int ixj = tid ^ j;
            if (ixj > tid){
                unsigned long long a = s[tid], b = s[ixj];
                bool asc = (tid & k) == 0;
                if ((a > b) == asc){ s[tid] = b; s[ixj] = a; }
            }
            __syncthreads();
        }
    }
    unsigned long long key = s[tid];
    bool val = (key != SENT);
    unsigned int j = (unsigned int)key;
    const float* fp = f + (size_t)proj * AB;
    const float* xyz = proj ? xyz2 : xyz1;
    float4 o = make_float4(0.f, 0.f, 0.f, 0.f);
    if (val){
        o.x = xyz[(size_t)j * 3 + 0];
        o.y = xyz[(size_t)j * 3 + 1];
        o.z = xyz[(size_t)j * 3 + 2];
        o.w = fp[j];                    // radius
    }
    pr[proj * KK + tid] = o;
    vb[proj * KK + tid] = val ? 1u : 0u;
    if (proj == 1){
        int row = KK + tid;
        out[row * 3 + 0] = o.x;
        out[row * 3 + 1] = o.y;
        out[row * 3 + 2] = o.z;
        out[2 * KK * 3 + row] = o.w;            // radius block at 6144
        out[2 * KK * 3 + 2 * KK + row] = val ? 1.0f : 0.0f;  // valid block at 8192
    }
}

// ---------------- dedup: suppress peaks1 within THR of any valid peak2
__global__ __launch_bounds__(256) void k_dedup(const float4* __restrict__ pr,
        const unsigned int* __restrict__ vb, float* __restrict__ out){
    const float THRF = (float)(6.283185307179586 / 256.0);
    int k = blockIdx.x * 256 + threadIdx.x;
    float4 m = pr[k];
    bool v1 = vb[k] != 0;
    __shared__ float4 tile[256];
    __shared__ unsigned int tv[256];
    bool close = false;
    for (int t = 0; t < 4; ++t){
        tile[threadIdx.x] = pr[KK + t * 256 + threadIdx.x];
        tv[threadIdx.x] = vb[KK + t * 256 + threadIdx.x];
        __syncthreads();
        if (v1 && !close){
            #pragma clang fp contract(off)
            for (int jj = 0; jj < 256; ++jj){
                if (tv[jj]){
                    float dx = m.x - tile[jj].x;
                    float dy = m.y - tile[jj].y;
                    float dz = m.z - tile[jj].z;
                    float d2 = dx * dx + dy * dy + dz * dz;
                    if (sqrtf(d2) < THRF){ close = true; break; }
                }
            }
        }
        __syncthreads();
    }
    bool keep = v1 && !close;
    out[k * 3 + 0] = keep ? m.x : 0.0f;
    out[k * 3 + 1] = keep ? m.y : 0.0f;
    out[k * 3 + 2] = keep ? m.z : 0.0f;
    out[2 * KK * 3 + k] = keep ? m.w : 0.0f;
    out[2 * KK * 3 + 2 * KK + k] = keep ? 1.0f : 0.0f;
}

extern "C" void kernel_launch(void* const* d_in, const int* in_sizes, int n_in,
                              void* d_out, int out_size, void* d_ws, size_t ws_size,
                              hipStream_t stream){
    const float* sig  = (const float*)d_in[0];
    const float* sh1  = (const float*)d_in[1];
    const float* sh2  = (const float*)d_in[2];
    const float* xyz1 = (const float*)d_in[3];
    const float* xyz2 = (const float*)d_in[4];
    float* out = (float*)d_out;
    char* ws = (char*)d_ws;

    // workspace layout (needs ~3.3 MB)
    float* f                  = (float*)(ws);                 // 2*AB*4   = 1,032,192 B
    unsigned long long* cand  = (unsigned long long*)(ws + 0x100000); // 2*AB*8 = 2,064,384 B
    unsigned int* counts      = (unsigned int*)(ws + 0x300000);       // 8 B
    unsigned long long* sel   = (unsigned long long*)(ws + 0x300100); // 16 KB
    float4* pr                = (float4*)(ws + 0x310000);             // 32 KB
    unsigned int* vb          = (unsigned int*)(ws + 0x320000);       // 8 KB

    hipMemsetAsync(counts, 0, 2 * sizeof(unsigned int), stream);

    k_gemv<<<dim3(AB / 4 / 256, 2), dim3(256), 0, stream>>>(sig, sh1, sh2, f);
    k_mask<<<dim3(AB / 256, 2), dim3(256), 0, stream>>>(f, cand, counts);
    k_select<<<dim3(1, 2), dim3(1024), 0, stream>>>(cand, counts, sel);
    k_sortgather<<<dim3(1, 2), dim3(1024), 0, stream>>>(sel, f, xyz1, xyz2, pr, vb, out);
    k_dedup<<<dim3(4, 1), dim3(256), 0, stream>>>(pr, vb, out);
}

// Round 3
// 223.149 us; speedup vs baseline: 1.8273x; 1.8273x over previous
//
#include <hip/hip_runtime.h>
#include <hip/hip_bf16.h>
#include <stdint.h>

#define NSH 256
#define AG 512          // alpha grid
#define BG 252          // beta grid
#define AB (AG*BG)      // 129024
#define KK 1024
#define SENT 0xFFFFFFFFFFFFFFFFull

// monotone float->uint map: ascending uint == ascending float
static __device__ __forceinline__ unsigned int fkey(float v){
    unsigned int u = __float_as_uint(v);
    u ^= (u >> 31) ? 0xFFFFFFFFu : 0x80000000u;
    return u;
}

// ---------------- GEMV: f[j] = sum_i sig[i]*sh[i*AB+j], sequential FMA i=0..255
__global__ __launch_bounds__(256) void k_gemv(const float* __restrict__ sig,
        const float* __restrict__ sh1, const float* __restrict__ sh2,
        float* __restrict__ f){
    __shared__ float s[NSH];
    s[threadIdx.x] = sig[threadIdx.x];
    __syncthreads();
    const float* sh = blockIdx.y ? sh2 : sh1;
    float* fo = f + (size_t)blockIdx.y * AB;
    size_t j4 = ((size_t)blockIdx.x * 256 + threadIdx.x) * 4;
    const float* p = sh + j4;
    float a0 = 0.f, a1 = 0.f, a2 = 0.f, a3 = 0.f;
    #pragma unroll 8
    for (int i = 0; i < NSH; ++i){
        float4 v = *reinterpret_cast<const float4*>(p + (size_t)i * AB);
        float si = s[i];
        a0 = fmaf(si, v.x, a0);
        a1 = fmaf(si, v.y, a1);
        a2 = fmaf(si, v.z, a2);
        a3 = fmaf(si, v.w, a3);
    }
    float4 o; o.x = a0; o.y = a1; o.z = a2; o.w = a3;
    *reinterpret_cast<float4*>(fo + j4) = o;
}

// ---------------- mask + pack candidate keys (wave-aggregated atomics)
__global__ __launch_bounds__(256) void k_mask(const float* __restrict__ f,
        unsigned long long* __restrict__ cand, unsigned int* __restrict__ counts){
    int proj = blockIdx.y;
    const float* fp = f + (size_t)proj * AB;
    int j = blockIdx.x * 256 + threadIdx.x;
    bool pred = false;
    unsigned long long key = 0;
    {
        int a = j / BG, b = j - a * BG;
        if (a > 0 && a < AG - 1 && b > 0 && b < BG - 1){
            float v = fp[j];
            pred = (v > fp[j-1]) && (v > fp[j+1]) && (v > fp[j-BG]) && (v > fp[j+BG]);
            if (pred)
                key = (((unsigned long long)(~fkey(v))) << 32) | (unsigned int)j;
        }
    }
    unsigned long long bal = __ballot(pred);
    if (bal){
        int lane = threadIdx.x & 63;
        int leader = __ffsll(bal) - 1;
        unsigned int base = 0;
        if (lane == leader) base = atomicAdd(&counts[proj], (unsigned int)__popcll(bal));
        base = __shfl(base, leader);
        if (pred){
            unsigned int off = (unsigned int)__popcll(bal & ((1ull << lane) - 1ull));
            cand[(size_t)proj * AB + base + off] = key;
        }
    }
}

// ---------------- single-block radix-select of K smallest 64-bit keys
__global__ __launch_bounds__(1024) void k_select(const unsigned long long* __restrict__ cand,
        const unsigned int* __restrict__ counts, unsigned long long* __restrict__ sel){
    int proj = blockIdx.y;
    const unsigned long long* cp = cand + (size_t)proj * AB;
    unsigned long long* sp = sel + proj * KK;
    unsigned int count = counts[proj];
    int tid = threadIdx.x;
    if (count <= KK){
        if (tid < KK) sp[tid] = SENT;               // pad
        if (tid < (int)count) sp[tid] = cp[tid];    // same thread overwrites same slot
        return;
    }
    __shared__ unsigned int hist[256];
    __shared__ unsigned int sbin, sremk;
    unsigned long long prefix = 0, pmask = 0;
    unsigned int remk = KK;
    for (int lvl = 7; lvl >= 0; --lvl){
        int shft = lvl * 8;
        if (tid < 256) hist[tid] = 0;
        __syncthreads();
        for (unsigned int i = tid; i < count; i += 1024){
            unsigned long long k = cp[i];
            if ((k & pmask) == prefix)
                atomicAdd(&hist[(unsigned int)(k >> shft) & 255u], 1u);
        }
        __syncthreads();
        if (tid == 0){
            unsigned int c = 0;
            for (int b = 0; b < 256; ++b){
                unsigned int h = hist[b];
                if (c + h >= remk){ sbin = (unsigned int)b; sremk = remk - c; break; }
                c += h;
            }
        }
        __syncthreads();
        prefix |= ((unsigned long long)sbin) << shft;
        pmask  |= 0xFFull << shft;
        remk = sremk;
        __syncthreads();
    }
    // prefix == K-th smallest key (keys unique: value bits + index)
    __shared__ unsigned int pos;
    if (tid == 0) pos = 0;
    __syncthreads();
    for (unsigned int i = tid; i < count; i += 1024){
        unsigned long long k = cp[i];
        if (k <= prefix){
            unsigned int p = atomicAdd(&pos, 1u);
            sp[p] = k;
        }
    }
}

// ---------------- bitonic sort 1024 keys + gather peaks/radius/valid
__global__ __launch_bounds__(1024) void k_sortgather(const unsigned long long* __restrict__ sel,
        const float* __restrict__ f, const float* __restrict__ xyz1,
        const float* __restrict__ xyz2, float4* __restrict__ pr,
        unsigned int* __restrict__ vb, float* __restrict__ out){
    int proj = blockIdx.y;
    int tid = threadIdx.x;
    __shared__ unsigned long long s[KK];
    s[tid] = sel[proj * KK + tid];
    __syncthreads();
    for (int k = 2; k <= KK; k <<= 1){
        for (int j = k >> 1; j > 0; j >>= 1){
            int ixj = tid ^ j;
            if (ixj > tid){
                unsigned long long a = s[tid], b = s[ixj];
                bool asc = (tid & k) == 0;
                if ((a > b) == asc){ s[tid] = b; s[ixj] = a; }
            }
            __syncthreads();
        }
    }
    unsigned long long key = s[tid];
    bool val = (key != SENT);
    unsigned int j = (unsigned int)key;
    const float* fp = f + (size_t)proj * AB;
    const float* xyz = proj ? xyz2 : xyz1;
    float4 o = make_float4(0.f, 0.f, 0.f, 0.f);
    if (val){
        o.x = xyz[(size_t)j * 3 + 0];
        o.y = xyz[(size_t)j * 3 + 1];
        o.z = xyz[(size_t)j * 3 + 2];
        o.w = fp[j];                    // radius
    }
    pr[proj * KK + tid] = o;
    vb[proj * KK + tid] = val ? 1u : 0u;
    if (proj == 1){
        int row = KK + tid;
        out[row * 3 + 0] = o.x;
        out[row * 3 + 1] = o.y;
        out[row * 3 + 2] = o.z;
        out[2 * KK * 3 + row] = o.w;            // radius block at 6144
        out[2 * KK * 3 + 2 * KK + row] = val ? 1.0f : 0.0f;  // valid block at 8192
    }
}

// ---------------- dedup pass 1: branchless distance tests -> suppress mask
// grid (4,4): block (bx,by) tests k1 in [bx*256,bx*256+256) vs j2 in [by*256,by*256+256)
__global__ __launch_bounds__(256) void k_dedup_mask(const float4* __restrict__ pr,
        const unsigned int* __restrict__ vb, unsigned int* __restrict__ suppress){
    const float THRF = (float)(6.283185307179586 / 256.0);
    int tid = threadIdx.x;
    __shared__ float sx[256], sy[256], sz[256];
    {
        int j = blockIdx.y * 256 + tid;
        float4 t = pr[KK + j];
        bool v2 = vb[KK + j] != 0;
        sx[tid] = v2 ? t.x : 1e9f;   // sentinel: invalid peak2 is "far away"
        sy[tid] = v2 ? t.y : 1e9f;
        sz[tid] = v2 ? t.z : 1e9f;
    }
    __syncthreads();
    int k = blockIdx.x * 256 + tid;
    float4 m = pr[k];
    bool close = false;
    {
        #pragma clang fp contract(off)
        #pragma unroll 8
        for (int jj = 0; jj < 256; ++jj){
            float dx = m.x - sx[jj];
            float dy = m.y - sy[jj];
            float dz = m.z - sz[jj];
            float d2 = dx * dx + dy * dy + dz * dz;
            close = close | (sqrtf(d2) < THRF);
        }
    }
    if (close) atomicOr(&suppress[k], 1u);
}

// ---------------- dedup pass 2: write rows 0..1023
__global__ __launch_bounds__(256) void k_out1(const float4* __restrict__ pr,
        const unsigned int* __restrict__ vb, const unsigned int* __restrict__ suppress,
        float* __restrict__ out){
    int k = blockIdx.x * 256 + threadIdx.x;
    float4 m = pr[k];
    bool keep = (vb[k] != 0) && (suppress[k] == 0);
    out[k * 3 + 0] = keep ? m.x : 0.0f;
    out[k * 3 + 1] = keep ? m.y : 0.0f;
    out[k * 3 + 2] = keep ? m.z : 0.0f;
    out[2 * KK * 3 + k] = keep ? m.w : 0.0f;                 // radius block
    out[2 * KK * 3 + 2 * KK + k] = keep ? 1.0f : 0.0f;       // valid block
}

extern "C" void kernel_launch(void* const* d_in, const int* in_sizes, int n_in,
                              void* d_out, int out_size, void* d_ws, size_t ws_size,
                              hipStream_t stream){
    const float* sig  = (const float*)d_in[0];
    const float* sh1  = (const float*)d_in[1];
    const float* sh2  = (const float*)d_in[2];
    const float* xyz1 = (const float*)d_in[3];
    const float* xyz2 = (const float*)d_in[4];
    float* out = (float*)d_out;
    char* ws = (char*)d_ws;

    // workspace layout (needs ~3.3 MB)
    float* f                  = (float*)(ws);                         // 2*AB*4
    unsigned long long* cand  = (unsigned long long*)(ws + 0x100000); // 2*AB*8
    unsigned int* counts      = (unsigned int*)(ws + 0x300000);       // 8 B
    unsigned long long* sel   = (unsigned long long*)(ws + 0x300100); // 16 KB
    float4* pr                = (float4*)(ws + 0x310000);             // 32 KB
    unsigned int* vb          = (unsigned int*)(ws + 0x320000);       // 8 KB
    unsigned int* suppress    = (unsigned int*)(ws + 0x328000);       // 4 KB

    (void)hipMemsetAsync(counts, 0, 2 * sizeof(unsigned int), stream);
    (void)hipMemsetAsync(suppress, 0, KK * sizeof(unsigned int), stream);

    k_gemv<<<dim3(AB / 4 / 256, 2), dim3(256), 0, stream>>>(sig, sh1, sh2, f);
    k_mask<<<dim3(AB / 256, 2), dim3(256), 0, stream>>>(f, cand, counts);
    k_select<<<dim3(1, 2), dim3(1024), 0, stream>>>(cand, counts, sel);
    k_sortgather<<<dim3(1, 2), dim3(1024), 0, stream>>>(sel, f, xyz1, xyz2, pr, vb, out);
    k_dedup_mask<<<dim3(4, 4), dim3(256), 0, stream>>>(pr, vb, suppress);
    k_out1<<<dim3(4, 1), dim3(256), 0, stream>>>(pr, vb, suppress, out);
}

// Round 4
// 180.890 us; speedup vs baseline: 2.2542x; 1.2336x over previous
//
#include <hip/hip_runtime.h>
#include <hip/hip_bf16.h>
#include <stdint.h>

#define NSH 256
#define AG 512          // alpha grid
#define BG 252          // beta grid
#define AB (AG*BG)      // 129024
#define KK 1024
#define SENT 0xFFFFFFFFFFFFFFFFull

// monotone float->uint map: ascending uint == ascending float
static __device__ __forceinline__ unsigned int fkey(float v){
    unsigned int u = __float_as_uint(v);
    u ^= (u >> 31) ? 0xFFFFFFFFu : 0x80000000u;
    return u;
}

// ---------------- GEMV: f[j] = sum_i sig[i]*sh[i*AB+j], sequential FMA i=0..255
// 1 output/thread -> 1008 blocks (~16 waves/CU) for HBM latency hiding.
__global__ __launch_bounds__(256) void k_gemv(const float* __restrict__ sig,
        const float* __restrict__ sh1, const float* __restrict__ sh2,
        float* __restrict__ f){
    __shared__ float s[NSH];
    s[threadIdx.x] = sig[threadIdx.x];
    __syncthreads();
    int proj = blockIdx.y;
    const float* sh = proj ? sh2 : sh1;
    int j = blockIdx.x * 256 + threadIdx.x;
    const float* p = sh + j;
    float a = 0.f;
    #pragma unroll 16
    for (int i = 0; i < NSH; ++i)
        a = fmaf(s[i], p[(size_t)i * AB], a);
    f[(size_t)proj * AB + j] = a;
}

// ---------------- mask + pack candidate keys (wave-aggregated atomics)
__global__ __launch_bounds__(256) void k_mask(const float* __restrict__ f,
        unsigned long long* __restrict__ cand, unsigned int* __restrict__ counts){
    int proj = blockIdx.y;
    const float* fp = f + (size_t)proj * AB;
    int j = blockIdx.x * 256 + threadIdx.x;
    bool pred = false;
    unsigned long long key = 0;
    {
        int a = j / BG, b = j - a * BG;
        if (a > 0 && a < AG - 1 && b > 0 && b < BG - 1){
            float v = fp[j];
            pred = (v > fp[j-1]) && (v > fp[j+1]) && (v > fp[j-BG]) && (v > fp[j+BG]);
            if (pred)
                key = (((unsigned long long)(~fkey(v))) << 32) | (unsigned int)j;
        }
    }
    unsigned long long bal = __ballot(pred);
    if (bal){
        int lane = threadIdx.x & 63;
        int leader = __ffsll(bal) - 1;
        unsigned int base = 0;
        if (lane == leader) base = atomicAdd(&counts[proj], (unsigned int)__popcll(bal));
        base = __shfl(base, leader);
        if (pred){
            unsigned int off = (unsigned int)__popcll(bal & ((1ull << lane) - 1ull));
            cand[(size_t)proj * AB + base + off] = key;
        }
    }
}

// ---------------- single-block radix-select of K smallest 64-bit keys
// bin choice is wave-parallel (shfl scan) -- no serial 256-bin walk.
__global__ __launch_bounds__(1024) void k_select(const unsigned long long* __restrict__ cand,
        const unsigned int* __restrict__ counts, unsigned long long* __restrict__ sel){
    int proj = blockIdx.y;
    const unsigned long long* cp = cand + (size_t)proj * AB;
    unsigned long long* sp = sel + proj * KK;
    unsigned int count = counts[proj];
    int tid = threadIdx.x;
    if (count <= KK){
        if (tid < KK) sp[tid] = SENT;               // pad
        if (tid < (int)count) sp[tid] = cp[tid];    // same thread overwrites same slot
        return;
    }
    __shared__ unsigned int hist[256];
    __shared__ unsigned int sbin, sremk;
    unsigned long long prefix = 0, pmask = 0;
    unsigned int remk = KK;
    for (int lvl = 7; lvl >= 0; --lvl){
        int shft = lvl * 8;
        if (tid < 256) hist[tid] = 0;
        __syncthreads();
        for (unsigned int i = tid; i < count; i += 1024){
            unsigned long long k = cp[i];
            if ((k & pmask) == prefix)
                atomicAdd(&hist[(unsigned int)(k >> shft) & 255u], 1u);
        }
        __syncthreads();
        if (tid < 64){
            unsigned int b0 = hist[tid*4+0], b1 = hist[tid*4+1];
            unsigned int b2 = hist[tid*4+2], b3 = hist[tid*4+3];
            unsigned int lsum = b0 + b1 + b2 + b3;
            unsigned int incl = lsum;
            #pragma unroll
            for (int off = 1; off < 64; off <<= 1){
                unsigned int v = __shfl_up(incl, off);
                if (tid >= off) incl += v;
            }
            unsigned int excl = incl - lsum;
            if (excl < remk && remk <= incl){
                unsigned int r = remk - excl;          // 1-based within this lane's 4 bins
                unsigned int c0 = b0, c01 = b0 + b1, c012 = b0 + b1 + b2;
                unsigned int bin, rr;
                if (r <= c0){ bin = tid*4+0; rr = r; }
                else if (r <= c01){ bin = tid*4+1; rr = r - c0; }
                else if (r <= c012){ bin = tid*4+2; rr = r - c01; }
                else { bin = tid*4+3; rr = r - c012; }
                sbin = bin; sremk = rr;
            }
        }
        __syncthreads();
        prefix |= ((unsigned long long)sbin) << shft;
        pmask  |= 0xFFull << shft;
        remk = sremk;
        __syncthreads();
    }
    // prefix == K-th smallest key (keys unique: value bits + index)
    __shared__ unsigned int pos;
    if (tid == 0) pos = 0;
    __syncthreads();
    for (unsigned int i = tid; i < count; i += 1024){
        unsigned long long k = cp[i];
        if (k <= prefix){
            unsigned int p = atomicAdd(&pos, 1u);
            sp[p] = k;
        }
    }
}

// ---------------- bitonic sort 1024 keys + gather peaks/radius/valid
__global__ __launch_bounds__(1024) void k_sortgather(const unsigned long long* __restrict__ sel,
        const float* __restrict__ f, const float* __restrict__ xyz1,
        const float* __restrict__ xyz2, float4* __restrict__ pr,
        unsigned int* __restrict__ vb, float* __restrict__ out){
    int proj = blockIdx.y;
    int tid = threadIdx.x;
    __shared__ unsigned long long s[KK];
    s[tid] = sel[proj * KK + tid];
    __syncthreads();
    for (int k = 2; k <= KK; k <<= 1){
        for (int j = k >> 1; j > 0; j >>= 1){
            int ixj = tid ^ j;
            if (ixj > tid){
                unsigned long long a = s[tid], b = s[ixj];
                bool asc = (tid & k) == 0;
                if ((a > b) == asc){ s[tid] = b; s[ixj] = a; }
            }
            __syncthreads();
        }
    }
    unsigned long long key = s[tid];
    bool val = (key != SENT);
    unsigned int j = (unsigned int)key;
    const float* fp = f + (size_t)proj * AB;
    const float* xyz = proj ? xyz2 : xyz1;
    float4 o = make_float4(0.f, 0.f, 0.f, 0.f);
    if (val){
        o.x = xyz[(size_t)j * 3 + 0];
        o.y = xyz[(size_t)j * 3 + 1];
        o.z = xyz[(size_t)j * 3 + 2];
        o.w = fp[j];                    // radius
    }
    pr[proj * KK + tid] = o;
    vb[proj * KK + tid] = val ? 1u : 0u;
    if (proj == 1){
        int row = KK + tid;
        out[row * 3 + 0] = o.x;
        out[row * 3 + 1] = o.y;
        out[row * 3 + 2] = o.z;
        out[2 * KK * 3 + row] = o.w;            // radius block at 6144
        out[2 * KK * 3 + 2 * KK + row] = val ? 1.0f : 0.0f;  // valid block at 8192
    }
}

// ---------------- dedup pass 1: branchless distance tests -> suppress mask
__global__ __launch_bounds__(256) void k_dedup_mask(const float4* __restrict__ pr,
        const unsigned int* __restrict__ vb, unsigned int* __restrict__ suppress){
    const float THRF = (float)(6.283185307179586 / 256.0);
    int tid = threadIdx.x;
    __shared__ float sx[256], sy[256], sz[256];
    {
        int j = blockIdx.y * 256 + tid;
        float4 t = pr[KK + j];
        bool v2 = vb[KK + j] != 0;
        sx[tid] = v2 ? t.x : 1e9f;   // sentinel: invalid peak2 is "far away"
        sy[tid] = v2 ? t.y : 1e9f;
        sz[tid] = v2 ? t.z : 1e9f;
    }
    __syncthreads();
    int k = blockIdx.x * 256 + tid;
    float4 m = pr[k];
    bool close = false;
    {
        #pragma clang fp contract(off)
        #pragma unroll 8
        for (int jj = 0; jj < 256; ++jj){
            float dx = m.x - sx[jj];
            float dy = m.y - sy[jj];
            float dz = m.z - sz[jj];
            float d2 = dx * dx + dy * dy + dz * dz;
            close = close | (sqrtf(d2) < THRF);
        }
    }
    if (close) atomicOr(&suppress[k], 1u);
}

// ---------------- dedup pass 2: write rows 0..1023
__global__ __launch_bounds__(256) void k_out1(const float4* __restrict__ pr,
        const unsigned int* __restrict__ vb, const unsigned int* __restrict__ suppress,
        float* __restrict__ out){
    int k = blockIdx.x * 256 + threadIdx.x;
    float4 m = pr[k];
    bool keep = (vb[k] != 0) && (suppress[k] == 0);
    out[k * 3 + 0] = keep ? m.x : 0.0f;
    out[k * 3 + 1] = keep ? m.y : 0.0f;
    out[k * 3 + 2] = keep ? m.z : 0.0f;
    out[2 * KK * 3 + k] = keep ? m.w : 0.0f;                 // radius block
    out[2 * KK * 3 + 2 * KK + k] = keep ? 1.0f : 0.0f;       // valid block
}

extern "C" void kernel_launch(void* const* d_in, const int* in_sizes, int n_in,
                              void* d_out, int out_size, void* d_ws, size_t ws_size,
                              hipStream_t stream){
    const float* sig  = (const float*)d_in[0];
    const float* sh1  = (const float*)d_in[1];
    const float* sh2  = (const float*)d_in[2];
    const float* xyz1 = (const float*)d_in[3];
    const float* xyz2 = (const float*)d_in[4];
    float* out = (float*)d_out;
    char* ws = (char*)d_ws;

    // workspace layout (~3.3 MB)
    float* f                  = (float*)(ws);                         // 2*AB*4
    unsigned long long* cand  = (unsigned long long*)(ws + 0x100000); // 2*AB*8
    unsigned int* counts      = (unsigned int*)(ws + 0x300000);       // 8 B
    unsigned long long* sel   = (unsigned long long*)(ws + 0x300100); // 16 KB
    float4* pr                = (float4*)(ws + 0x310000);             // 32 KB
    unsigned int* vb          = (unsigned int*)(ws + 0x320000);       // 8 KB
    unsigned int* suppress    = (unsigned int*)(ws + 0x328000);       // 4 KB

    (void)hipMemsetAsync(counts, 0, 2 * sizeof(unsigned int), stream);
    (void)hipMemsetAsync(suppress, 0, KK * sizeof(unsigned int), stream);

    k_gemv<<<dim3(AB / 256, 2), dim3(256), 0, stream>>>(sig, sh1, sh2, f);
    k_mask<<<dim3(AB / 256, 2), dim3(256), 0, stream>>>(f, cand, counts);
    k_select<<<dim3(1, 2), dim3(1024), 0, stream>>>(cand, counts, sel);
    k_sortgather<<<dim3(1, 2), dim3(1024), 0, stream>>>(sel, f, xyz1, xyz2, pr, vb, out);
    k_dedup_mask<<<dim3(4, 4), dim3(256), 0, stream>>>(pr, vb, suppress);
    k_out1<<<dim3(4, 1), dim3(256), 0, stream>>>(pr, vb, suppress, out);
}